// Round 19
// baseline (3406.078 us; speedup 1.0000x reference)
//
#include <hip/hip_runtime.h>
#include <hip/hip_bf16.h>

// ---------------------------------------------------------------------------
// Bidirectional GRU encoder (Keras reset_after=true), B=64 S=512 U=256 V=32000
// Round 19: cross-CU N-split recurrence. 64 wgs = (dir, chain-group cg, side p);
//   sides p=0/1 own units [0,128)/[128,256) (all 3 gates) of 4 chains.
//   Per step: phase-A MFMA (own K-half, 12/wave) overlaps partner-h L3 read;
//   stage partner half to LDS; lds_barrier; phase-B MFMA (partner K-half);
//   lane-local epilogue (1 unit/lane); publish own h-half to L3 via atomicExch
//   (parity double-buffer) + monotonic flag after __syncthreads vmcnt drain.
//   All cross-wg traffic is device-scope atomic RMW (coherent at L3, no cache
//   flushes). Deadlock-free: 64 wgs < 256 CUs, partner never blocked by spin.
//   gemm k1: R16 natural-layout (coalesced). prep k0: side-split Upk.
// ws: [0,100663296) gx ; +786432 Wtb ; +786432 Upk ; @102236160 flags(1KB) ;
//     @102237184 hx (128 KB)
// ---------------------------------------------------------------------------

typedef short short8 __attribute__((ext_vector_type(8)));
typedef float f32x4 __attribute__((ext_vector_type(4)));

__device__ __forceinline__ unsigned short f2bf(float f) {
  unsigned int u = __float_as_uint(f);
  return (unsigned short)((u + 0x7fffu + ((u >> 16) & 1u)) >> 16);  // RNE
}
__device__ __forceinline__ float bf2f(unsigned short v) {
  return __uint_as_float((unsigned int)v << 16);
}
__device__ __forceinline__ float sigf(float x) {
  return __builtin_amdgcn_rcpf(1.f + __expf(-x));
}
__device__ __forceinline__ float tanhfast(float x) {
  return 1.f - 2.f * __builtin_amdgcn_rcpf(1.f + __expf(2.f * x));
}
__device__ __forceinline__ void lds_barrier() {
  __builtin_amdgcn_sched_barrier(0);
  asm volatile("s_waitcnt lgkmcnt(0)" ::: "memory");
  __builtin_amdgcn_s_barrier();
  __builtin_amdgcn_sched_barrier(0);
}

// ---------------- k0: merged prep (Wtb + side-split Upk) --------------------
// ids [0, 393216): Wtb[dir][c][k] = bf16(W[k][c])
// ids [393216, +49152): id2 = ((((dir*2+p)*8+w)*3+g)*8+kk)*64+lane
//   gcol = g*256 + p*128 + w*16 + (lane&15), k = kk*32 + (lane>>4)*8 + e
__global__ void __launch_bounds__(256) prep_kernel(
    const float* __restrict__ Wf, const float* __restrict__ Wb,
    const float* __restrict__ Uf, const float* __restrict__ Ub,
    unsigned short* __restrict__ Wtb, unsigned short* __restrict__ Upk) {
  int id = blockIdx.x * 256 + threadIdx.x;
  if (id < 2 * 768 * 256) {
    int dir = id / (768 * 256);
    int rem = id % (768 * 256);
    int c = rem / 256, k = rem % 256;
    const float* W = dir ? Wb : Wf;
    Wtb[id] = f2bf(W[(size_t)k * 768 + c]);
    return;
  }
  int id2 = id - 2 * 768 * 256;
  if (id2 >= 49152) return;
  int lane = id2 & 63;
  int kk = (id2 >> 6) & 7;
  int g = (id2 >> 9) % 3;
  int w = (id2 / 1536) & 7;
  int p = (id2 / 12288) & 1;
  int dir = id2 / 24576;
  const float* U = dir ? Ub : Uf;
  int gcol = g * 256 + p * 128 + w * 16 + (lane & 15);
  int k0 = kk * 32 + (lane >> 4) * 8;
  unsigned short* o = Upk + (size_t)id2 * 8;
#pragma unroll
  for (int e = 0; e < 8; ++e) o[e] = f2bf(U[(size_t)(k0 + e) * 768 + gcol]);
}

// ---------------- k1: gx = emb[x] @ W + bias, bf16 MFMA, natural layout -----
__global__ void __launch_bounds__(256) gx_mfma_kernel(
    const int* __restrict__ x, const float* __restrict__ emb,
    const unsigned short* __restrict__ Wtb,
    const float* __restrict__ bfv, const float* __restrict__ bbv,
    unsigned short* __restrict__ gx) {
  __shared__ __align__(16) unsigned short As[128 * 32];
  __shared__ __align__(16) unsigned short Bs[128 * 32];
  __shared__ int xid[128];

  int tid = threadIdx.x;
  int r0 = blockIdx.x * 128;
  int yt = blockIdx.y;
  int dir = (yt >= 6) ? 1 : 0;
  int c0 = (yt - dir * 6) * 128;
  const float* bv = dir ? bbv : bfv;
  const unsigned short* WtD = Wtb + (size_t)dir * 768 * 256;

  if (tid < 128) xid[tid] = x[r0 + tid];
  __syncthreads();

  int lane = tid & 63, w = tid >> 6;
  int wr = w >> 1, wc = w & 1;

  f32x4 acc[4][4] = {};

  for (int ks = 0; ks < 8; ++ks) {
#pragma unroll
    for (int i = 0; i < 2; ++i) {
      int s = tid + i * 256;
      int row = s >> 2, kslot = s & 3;
      int sw = kslot ^ ((row >> 2) & 3);
      const float* src = emb + (size_t)xid[row] * 256 + ks * 32 + kslot * 8;
      float4 f0 = *(const float4*)src;
      float4 f1 = *(const float4*)(src + 4);
      uint4 pa;
      pa.x = f2bf(f0.x) | ((unsigned)f2bf(f0.y) << 16);
      pa.y = f2bf(f0.z) | ((unsigned)f2bf(f0.w) << 16);
      pa.z = f2bf(f1.x) | ((unsigned)f2bf(f1.y) << 16);
      pa.w = f2bf(f1.z) | ((unsigned)f2bf(f1.w) << 16);
      *(uint4*)&As[row * 32 + sw * 8] = pa;
      uint4 pb = *(const uint4*)(WtD + (size_t)(c0 + row) * 256 + ks * 32 + kslot * 8);
      *(uint4*)&Bs[row * 32 + sw * 8] = pb;
    }
    __syncthreads();

    short8 a[4], b[4];
#pragma unroll
    for (int f = 0; f < 4; ++f) {
      int rowA = wr * 64 + f * 16 + (lane & 15);
      int swA = (lane >> 4) ^ ((rowA >> 2) & 3);
      a[f] = __builtin_bit_cast(short8, *(const uint4*)&As[rowA * 32 + swA * 8]);
      int rowB = wc * 64 + f * 16 + (lane & 15);
      int swB = (lane >> 4) ^ ((rowB >> 2) & 3);
      b[f] = __builtin_bit_cast(short8, *(const uint4*)&Bs[rowB * 32 + swB * 8]);
    }
#pragma unroll
    for (int fm = 0; fm < 4; ++fm)
#pragma unroll
      for (int fn = 0; fn < 4; ++fn)
        acc[fm][fn] = __builtin_amdgcn_mfma_f32_16x16x32_bf16(a[fm], b[fn], acc[fm][fn], 0, 0, 0);
    __syncthreads();
  }

#pragma unroll
  for (int fn = 0; fn < 4; ++fn) {
    int col = c0 + wc * 64 + fn * 16 + (lane & 15);
    float bias = bv[col] + (col < 512 ? bv[768 + col] : 0.f);
#pragma unroll
    for (int fm = 0; fm < 4; ++fm) {
      int rowb = r0 + wr * 64 + fm * 16 + (lane >> 4) * 4;
#pragma unroll
      for (int q = 0; q < 4; ++q) {
        gx[((size_t)dir * 32768 + rowb + q) * 768 + col] = f2bf(acc[fm][fn][q] + bias);
      }
    }
  }
}

// ---------------- k2: N-split MFMA recurrence -------------------------------
__global__ void __launch_bounds__(512, 1) gru_kernel(
    const unsigned short* __restrict__ Upk,
    const unsigned short* __restrict__ gx,   // [dir][32768][768] bf16 natural
    const int* __restrict__ x,
    const float* __restrict__ bfv, const float* __restrict__ bbv,
    float* __restrict__ out,
    int* __restrict__ flags,                 // [2][16][2] monotonic, zeroed
    unsigned int* __restrict__ hx) {         // [2][16][2][2][256] uints
  int wg = blockIdx.x;                 // 0..63
  int dir = wg >> 5, cg = (wg >> 1) & 15, p = wg & 1;
  int t = threadIdx.x;
  int w = t >> 6, l = t & 63;
  int G = l >> 4, cl = l & 15;
  int b = cg * 4 + G;
  int u = p * 128 + w * 16 + cl;       // this lane's global unit

  // h[16 rows][256 units] bf16, byte ^= ((row&7)<<4) swizzle, double-buffered
  __shared__ __align__(16) unsigned short h_lds[2][4096];

  // resident U B-fragments: 3 slots (z,r,h for this side/wave) x 8 K-frags
  short8 Ufr[3][8];
  {
    const unsigned short* ub = Upk + (size_t)((dir * 2 + p) * 8 + w) * 12288 + (size_t)l * 8;
#pragma unroll
    for (int g = 0; g < 3; ++g)
#pragma unroll
      for (int kk = 0; kk < 8; ++kk)
        Ufr[g][kk] = __builtin_bit_cast(short8, *(const uint4*)(ub + (g * 8 + kk) * 512));
  }
  {
    uint4 z = {0u, 0u, 0u, 0u};
    ((uint4*)h_lds)[t] = z;
    ((uint4*)h_lds)[512 + t] = z;
  }

  const float* bv = dir ? bbv : bfv;
  const float brh = bv[1280 + u];

  int* flag_own = flags + (dir * 16 + cg) * 2 + p;
  int* flag_par = flags + (dir * 16 + cg) * 2 + (p ^ 1);
  unsigned int* hx_wr = hx + (size_t)((dir * 16 + cg) * 2 + p) * 512;
  unsigned int* hx_rd = hx + (size_t)((dir * 16 + cg) * 2 + (p ^ 1)) * 512;

  // running pointers: gx natural, row stride 1536 B
  int t0 = dir ? 511 : 0;
  long sdelta = dir ? -1536 : 1536;
  const char* gp = (const char*)gx
      + (((size_t)dir * 32768 + (size_t)b * 512 + t0) * 768 + u) * 2;
  const int* xp = x + b * 512 + t0;
  int xdelta = dir ? -1 : 1;

  unsigned short gz = *(const unsigned short*)(gp);
  unsigned short gr = *(const unsigned short*)(gp + 512);
  unsigned short gh = *(const unsigned short*)(gp + 1024);
  int xv = *xp;

  float h_old = 0.f;
  int f_pre = 0;
  __syncthreads();

  int cur = 0;
  int tcur = t0;
  for (int s = 0; s < 512; ++s) {
    // --- partner h(s-1): flag-gated L3 read (waves 0-3 only) ---
    unsigned int pk = 0u;
    if (s > 0 && w < 4) {
      if (f_pre < s) {
        int ff;
        do {
          int f1 = (l == 0) ? atomicAdd(flag_par, 0) : 0;
          ff = __shfl(f1, 0);
        } while (ff < s);
        f_pre = ff;
      }
      pk = atomicAdd(&hx_rd[(size_t)((s - 1) & 1) * 256 + t], 0u);
    }

    // --- prefetch next step's gx + mask ---
    const char* gpn = (s < 511) ? gp + sdelta : gp;
    const int* xpn = (s < 511) ? xp + xdelta : xp;
    unsigned short nz = *(const unsigned short*)(gpn);
    unsigned short nr = *(const unsigned short*)(gpn + 512);
    unsigned short nh = *(const unsigned short*)(gpn + 1024);
    int xn = *xpn;

    // --- phase A: own K-half (kk = 4p..4p+3), hides the L3 read ---
    f32x4 acc[3];
#pragma unroll
    for (int g = 0; g < 3; ++g) acc[g] = (f32x4){0.f, 0.f, 0.f, 0.f};
    const char* hb = (const char*)(&h_lds[cur][0]);
    int amask = (cl & 7) << 4;
#pragma unroll
    for (int k2 = 0; k2 < 4; ++k2) {
      int kk = 4 * p + k2;
      short8 a = __builtin_bit_cast(short8,
          *(const uint4*)(hb + cl * 512 + (((kk << 6) | (G << 4)) ^ amask)));
#pragma unroll
      for (int g = 0; g < 3; ++g)
        acc[g] = __builtin_amdgcn_mfma_f32_16x16x32_bf16(a, Ufr[g][kk], acc[g], 0, 0, 0);
    }

    // --- stage partner half into h_lds[cur] (disjoint from phase-A reads) ---
    if (s > 0 && w < 4) {
      int G2 = t >> 6, m = t & 63;
      *(unsigned int*)((char*)(&h_lds[cur][0]) + G2 * 2048
                       + ((((p ^ 1) * 256 + 4 * m)) ^ ((G2 & 1) << 6))) = pk;
    }
    lds_barrier();

    // --- phase B: partner K-half ---
#pragma unroll
    for (int k2 = 0; k2 < 4; ++k2) {
      int kk = 4 * (p ^ 1) + k2;
      short8 a = __builtin_bit_cast(short8,
          *(const uint4*)(hb + cl * 512 + (((kk << 6) | (G << 4)) ^ amask)));
#pragma unroll
      for (int g = 0; g < 3; ++g)
        acc[g] = __builtin_amdgcn_mfma_f32_16x16x32_bf16(a, Ufr[g][kk], acc[g], 0, 0, 0);
    }

    // --- epilogue: 1 unit/lane, chain G at C row 4G -> acc[g][0] ---
    float z = sigf(bf2f(gz) + acc[0][0]);
    float r = sigf(bf2f(gr) + acc[1][0]);
    float hh = tanhfast(bf2f(gh) + r * (acc[2][0] + brh));
    float hn = hh + z * (h_old - hh);
    hn = (xv == 0) ? h_old : hn;            // masked: carry state
    h_old = hn;
    unsigned short hb16 = f2bf(hn);
    // own half -> next LDS buffer
    *(unsigned short*)((char*)(&h_lds[cur ^ 1][0]) + G * 2048
                       + ((u * 2) ^ ((G & 1) << 6))) = hb16;
    // publish own half to L3 (parity buffer), even-cl lanes pack 2 units
    {
      unsigned int hnb = hb16;
      unsigned int prt = (unsigned int)__shfl_xor((int)hnb, 1);
      if (!(cl & 1)) {
        int i = G * 64 + w * 8 + (cl >> 1);
        atomicExch(&hx_wr[(size_t)(s & 1) * 256 + i], hnb | (prt << 16));
      }
    }
    atomicAdd(&out[((size_t)b << 17) + (size_t)tcur * 256 + u], hn);

    __syncthreads();                         // vmcnt drain: hx + out complete
    if (t == 0) atomicExch(flag_own, s + 1);
    if (w < 4) {                             // pre-read partner flag for s+1
      int f1 = (l == 0) ? atomicAdd(flag_par, 0) : 0;
      f_pre = __shfl(f1, 0);
    }

    gz = nz; gr = nr; gh = nh; xv = xn;
    gp = gpn; xp = xpn;
    tcur += (s < 511) ? xdelta : 0;
    cur ^= 1;
  }
}

// ---------------------------------------------------------------------------
extern "C" void kernel_launch(void* const* d_in, const int* in_sizes, int n_in,
                              void* d_out, int out_size, void* d_ws, size_t ws_size,
                              hipStream_t stream) {
  const int*   x   = (const int*)d_in[0];
  const float* emb = (const float*)d_in[1];
  const float* Wf  = (const float*)d_in[2];
  const float* Uf  = (const float*)d_in[3];
  const float* bf_ = (const float*)d_in[4];
  const float* Wb  = (const float*)d_in[5];
  const float* Ub  = (const float*)d_in[6];
  const float* bb_ = (const float*)d_in[7];
  float* out = (float*)d_out;

  unsigned short* gxp = (unsigned short*)d_ws;                        // 100663296 B
  unsigned short* Wtb = (unsigned short*)((char*)d_ws + 100663296);   // 786432 B
  unsigned short* Upk = (unsigned short*)((char*)d_ws + 100663296 + 786432);  // 786432 B
  int*            flg = (int*)((char*)d_ws + 102236160);              // 1 KB
  unsigned int*   hx  = (unsigned int*)((char*)d_ws + 102237184);     // 128 KB

  hipMemsetAsync(d_out, 0, (size_t)out_size * sizeof(float), stream);
  hipMemsetAsync(flg, 0, 1024, stream);

  prep_kernel<<<1728, 256, 0, stream>>>(Wf, Wb, Uf, Ub, Wtb, Upk);
  gx_mfma_kernel<<<dim3(256, 12), 256, 0, stream>>>(x, emb, Wtb, bf_, bb_, gxp);
  gru_kernel<<<64, 512, 0, stream>>>(Upk, gxp, x, bf_, bb_, out, flg, hx);
}

// Round 20
// 608.624 us; speedup vs baseline: 5.5964x; 5.5964x over previous
//
#include <hip/hip_runtime.h>
#include <hip/hip_bf16.h>

// ---------------------------------------------------------------------------
// Bidirectional GRU encoder (Keras reset_after=true), B=64 S=512 U=256 V=32000
// FINAL (= Round 12, the verified optimum): MFMA recurrence.
//   32 wgs = (dir, 4-batch group); 512 thr = 8 waves (2/SIMD, lb(512,1)).
//   Wave w owns 6 N-slots (z,r,h x col-groups {2w,2w+1}); U B-frags 6x8
//   short8 = 192 regs resident in the unified VGPR/AGPR file (MFMA-native).
//   Chains at C rows {0,4,8,12}; lane-local epilogue; raw lds_barrier
//   (LDS-only, no vmcnt drain -> atomics/prefetch retire off-path);
//   gx SoA [dir][t][gate][8192 dwords] prefetched 1 step ahead via running
//   byte pointers.
//   Structural bound: 512 serial steps x (384 mfma x 4.85 cyc + ~590 residue)
//   ~= 523 us gru; + memset/prep/gemm ~= 606 us total. Six residue-trim
//   variants (R13-R18) and a cross-CU N-split (R19) all regressed.
// ws: [0,100663296) gx4 ; +786432 Wtb ; +786432 Upk   (~102.2 MB)
// ---------------------------------------------------------------------------

typedef short short8 __attribute__((ext_vector_type(8)));
typedef float f32x4 __attribute__((ext_vector_type(4)));

__device__ __forceinline__ unsigned short f2bf(float f) {
  unsigned int u = __float_as_uint(f);
  return (unsigned short)((u + 0x7fffu + ((u >> 16) & 1u)) >> 16);  // RNE
}
__device__ __forceinline__ float blo(unsigned int u) { return __uint_as_float(u << 16); }
__device__ __forceinline__ float bhi(unsigned int u) { return __uint_as_float(u & 0xffff0000u); }
__device__ __forceinline__ float sigf(float x) {
  return __builtin_amdgcn_rcpf(1.f + __expf(-x));
}
__device__ __forceinline__ float tanhfast(float x) {
  return 1.f - 2.f * __builtin_amdgcn_rcpf(1.f + __expf(2.f * x));
}
// LDS-only barrier: order h_lds exchange without draining vmem queues.
__device__ __forceinline__ void lds_barrier() {
  __builtin_amdgcn_sched_barrier(0);
  asm volatile("s_waitcnt lgkmcnt(0)" ::: "memory");
  __builtin_amdgcn_s_barrier();
  __builtin_amdgcn_sched_barrier(0);
}

// ---------------- k0a: Wtb[dir][c][k] = bf16(W[k][c]) -----------------------
__global__ void __launch_bounds__(256) wt_prep_kernel(const float* __restrict__ Wf,
                                                      const float* __restrict__ Wb,
                                                      unsigned short* __restrict__ Wtb) {
  int o = blockIdx.x * 256 + threadIdx.x;
  if (o >= 2 * 768 * 256) return;
  int dir = o / (768 * 256);
  int rem = o % (768 * 256);
  int c = rem / 256, k = rem % 256;
  const float* W = dir ? Wb : Wf;
  Wtb[o] = f2bf(W[(size_t)k * 768 + c]);
}

// ---------------- k0b: U -> MFMA B-fragments (8-wave split) -----------------
// id = (((dir*8+w)*6+s)*8+kk)*64+lane. s = g*2+d:
// gcol = g*256 + w*32 + d*16 + (lane&15), k = kk*32 + (lane>>4)*8 + e.
__global__ void __launch_bounds__(256) u_prep_kernel(const float* __restrict__ Uf,
                                                     const float* __restrict__ Ub,
                                                     unsigned short* __restrict__ Upk) {
  int id = blockIdx.x * 256 + threadIdx.x;
  if (id >= 2 * 8 * 6 * 8 * 64) return;  // 49152
  int lane = id & 63;
  int kk = (id >> 6) & 7;
  int s = (id >> 9) % 6;
  int w = (id / 3072) & 7;
  int dir = id / 24576;
  const float* U = dir ? Ub : Uf;
  int g = s >> 1, d = s & 1;
  int gcol = g * 256 + w * 32 + d * 16 + (lane & 15);
  int k0 = kk * 32 + (lane >> 4) * 8;
  unsigned short* o = Upk + (size_t)id * 8;
#pragma unroll
  for (int e = 0; e < 8; ++e) o[e] = f2bf(U[(size_t)(k0 + e) * 768 + gcol]);
}

// ---------------- k1: gx4 = emb[x] @ W + bias, bf16 MFMA, SoA out -----------
// gx4 ushort idx = ((dir*512+t)*3+g)*16384 + ((bg*8+w2)*64 + G*16+cl2)*2 + d
__global__ void __launch_bounds__(256) gx_mfma_kernel(
    const int* __restrict__ x, const float* __restrict__ emb,
    const unsigned short* __restrict__ Wtb,
    const float* __restrict__ bfv, const float* __restrict__ bbv,
    unsigned short* __restrict__ gx4) {
  __shared__ __align__(16) unsigned short As[128 * 32];
  __shared__ __align__(16) unsigned short Bs[128 * 32];
  __shared__ int xid[128];

  int tid = threadIdx.x;
  int r0 = blockIdx.x * 128;
  int yt = blockIdx.y;
  int dir = (yt >= 6) ? 1 : 0;
  int c0 = (yt - dir * 6) * 128;
  const float* bv = dir ? bbv : bfv;
  const unsigned short* WtD = Wtb + (size_t)dir * 768 * 256;

  if (tid < 128) xid[tid] = x[r0 + tid];
  __syncthreads();

  int lane = tid & 63, w = tid >> 6;
  int wr = w >> 1, wc = w & 1;

  f32x4 acc[4][4] = {};

  for (int ks = 0; ks < 8; ++ks) {
#pragma unroll
    for (int i = 0; i < 2; ++i) {
      int s = tid + i * 256;
      int row = s >> 2, kslot = s & 3;
      int sw = kslot ^ ((row >> 2) & 3);
      const float* src = emb + (size_t)xid[row] * 256 + ks * 32 + kslot * 8;
      float4 f0 = *(const float4*)src;
      float4 f1 = *(const float4*)(src + 4);
      uint4 pa;
      pa.x = f2bf(f0.x) | ((unsigned)f2bf(f0.y) << 16);
      pa.y = f2bf(f0.z) | ((unsigned)f2bf(f0.w) << 16);
      pa.z = f2bf(f1.x) | ((unsigned)f2bf(f1.y) << 16);
      pa.w = f2bf(f1.z) | ((unsigned)f2bf(f1.w) << 16);
      *(uint4*)&As[row * 32 + sw * 8] = pa;
      uint4 pb = *(const uint4*)(WtD + (size_t)(c0 + row) * 256 + ks * 32 + kslot * 8);
      *(uint4*)&Bs[row * 32 + sw * 8] = pb;
    }
    __syncthreads();

    short8 a[4], b[4];
#pragma unroll
    for (int f = 0; f < 4; ++f) {
      int rowA = wr * 64 + f * 16 + (lane & 15);
      int swA = (lane >> 4) ^ ((rowA >> 2) & 3);
      a[f] = __builtin_bit_cast(short8, *(const uint4*)&As[rowA * 32 + swA * 8]);
      int rowB = wc * 64 + f * 16 + (lane & 15);
      int swB = (lane >> 4) ^ ((rowB >> 2) & 3);
      b[f] = __builtin_bit_cast(short8, *(const uint4*)&Bs[rowB * 32 + swB * 8]);
    }
#pragma unroll
    for (int fm = 0; fm < 4; ++fm)
#pragma unroll
      for (int fn = 0; fn < 4; ++fn)
        acc[fm][fn] = __builtin_amdgcn_mfma_f32_16x16x32_bf16(a[fm], b[fn], acc[fm][fn], 0, 0, 0);
    __syncthreads();
  }

#pragma unroll
  for (int fn = 0; fn < 4; ++fn) {
    int col = c0 + wc * 64 + fn * 16 + (lane & 15);
    float bias = bv[col] + (col < 512 ? bv[768 + col] : 0.f);
    int g = col >> 8, u = col & 255;
    int w2 = u >> 5, d = (u >> 4) & 1, cl2 = u & 15;
#pragma unroll
    for (int fm = 0; fm < 4; ++fm) {
      int rowb = r0 + wr * 64 + fm * 16 + (lane >> 4) * 4;
#pragma unroll
      for (int q = 0; q < 4; ++q) {
        int row = rowb + q;
        int bb2 = row >> 9, tt2 = row & 511;
        int G = bb2 & 3, bg2 = bb2 >> 2;
        size_t idx = ((size_t)(dir * 512 + tt2) * 3 + g) * 16384
                     + (size_t)((bg2 * 8 + w2) * 64 + (G * 16 + cl2)) * 2 + d;
        gx4[idx] = f2bf(acc[fm][fn][q] + bias);
      }
    }
  }
}

// ---------------- k2: MFMA recurrence, raw barrier, running pointers --------
__global__ void __launch_bounds__(512, 1) gru_kernel(
    const unsigned short* __restrict__ Upk,
    const unsigned short* __restrict__ gx4,
    const int* __restrict__ x,
    const float* __restrict__ bfv, const float* __restrict__ bbv,
    float* __restrict__ out) {
  int wg = blockIdx.x;                 // 0..31
  int dir = wg >> 4, bg = wg & 15;
  int tid = threadIdx.x;
  int w = tid >> 6, l = tid & 63;
  int G = l >> 4, cl = l & 15;         // chain-in-group, unit-col
  int b = bg * 4 + G;

  // h[16 rows][256 units] bf16, byte ^= ((row&7)<<4) swizzle, double-buffered
  __shared__ __align__(16) unsigned short h_lds[2][4096];

  // resident U B-fragments: 6 slots x 8 K-frags = 192 regs
  short8 Ufr[6][8];
  {
    const unsigned short* ub = Upk + (size_t)(dir * 8 + w) * 24576 + (size_t)l * 8;
#pragma unroll
    for (int s = 0; s < 6; ++s)
#pragma unroll
      for (int kk = 0; kk < 8; ++kk)
        Ufr[s][kk] = __builtin_bit_cast(short8, *(const uint4*)(ub + (s * 8 + kk) * 512));
  }

  {
    uint4 z = {0u, 0u, 0u, 0u};
    ((uint4*)h_lds)[tid] = z;
    ((uint4*)h_lds)[512 + tid] = z;
  }

  const float* bv = dir ? bbv : bfv;
  float brh[2];
#pragma unroll
  for (int d = 0; d < 2; ++d) brh[d] = bv[1280 + w * 32 + d * 16 + cl];
  float* outb = out + ((size_t)b << 17);

  int amask = (cl & 7) << 4;
  float h_old[2] = {0.f, 0.f};

  // running pointers (byte-based), one step = 98304 B in gx4, 1 int in x
  int t0 = dir ? 511 : 0;
  long sdelta = dir ? -98304 : 98304;
  const char* gp = (const char*)gx4 + ((size_t)(dir * 512 + t0) * 98304)
                   + (size_t)((bg * 8 + w) * 64 + l) * 4;
  const int* xp = x + b * 512 + t0;
  int xdelta = dir ? -1 : 1;

  // prologue: load step 0's gx + mask
  unsigned int gq0 = *(const unsigned int*)(gp);
  unsigned int gq1 = *(const unsigned int*)(gp + 32768);
  unsigned int gq2 = *(const unsigned int*)(gp + 65536);
  int xv = *xp;
  __syncthreads();

  int cur = 0;
  int tcur = t0;
  for (int step = 0; step < 512; ++step) {
    // prefetch NEXT step (running pointers; redundant reload on last step)
    const char* gpn = (step < 511) ? gp + sdelta : gp;
    const int* xpn = (step < 511) ? xp + xdelta : xp;
    unsigned int gn0 = *(const unsigned int*)(gpn);
    unsigned int gn1 = *(const unsigned int*)(gpn + 32768);
    unsigned int gn2 = *(const unsigned int*)(gpn + 65536);
    int xn = *xpn;

    // --- MFMA phase: acc[s] = h @ U[slot s] ---
    f32x4 acc[6];
#pragma unroll
    for (int s = 0; s < 6; ++s) acc[s] = (f32x4){0.f, 0.f, 0.f, 0.f};
    const char* hb = (const char*)(&h_lds[cur][0]);
#pragma unroll
    for (int kk = 0; kk < 8; ++kk) {
      short8 a = __builtin_bit_cast(short8,
          *(const uint4*)(hb + cl * 512 + (((kk << 6) | (G << 4)) ^ amask)));
#pragma unroll
      for (int s = 0; s < 6; ++s)
        acc[s] = __builtin_amdgcn_mfma_f32_16x16x32_bf16(a, Ufr[s][kk], acc[s], 0, 0, 0);
    }

    // --- epilogue: chain G at C row 4G -> acc[s][0]; 2 units/lane ---
    char* hw = (char*)(&h_lds[cur ^ 1][0]);
#pragma unroll
    for (int d = 0; d < 2; ++d) {
      float gz = d ? bhi(gq0) : blo(gq0);
      float gr = d ? bhi(gq1) : blo(gq1);
      float gh = d ? bhi(gq2) : blo(gq2);
      float z = sigf(gz + acc[0 + d][0]);
      float r = sigf(gr + acc[2 + d][0]);
      float hh = tanhfast(gh + r * (acc[4 + d][0] + brh[d]));
      float hn = hh + z * (h_old[d] - hh);
      hn = (xv == 0) ? h_old[d] : hn;          // masked: carry state
      h_old[d] = hn;
      int u = w * 32 + d * 16 + cl;
      *(unsigned short*)(hw + G * 2048 + ((u * 2) ^ ((G & 1) << 6))) = f2bf(hn);
      atomicAdd(&outb[(size_t)tcur * 256 + u], hn);   // drains off-path
    }
    lds_barrier();                              // LDS-only, no vmcnt drain
    gq0 = gn0; gq1 = gn1; gq2 = gn2; xv = xn;
    gp = gpn; xp = xpn;
    tcur += (step < 511) ? xdelta : 0;
    cur ^= 1;
  }
}

// ---------------------------------------------------------------------------
extern "C" void kernel_launch(void* const* d_in, const int* in_sizes, int n_in,
                              void* d_out, int out_size, void* d_ws, size_t ws_size,
                              hipStream_t stream) {
  const int*   x   = (const int*)d_in[0];
  const float* emb = (const float*)d_in[1];
  const float* Wf  = (const float*)d_in[2];
  const float* Uf  = (const float*)d_in[3];
  const float* bf_ = (const float*)d_in[4];
  const float* Wb  = (const float*)d_in[5];
  const float* Ub  = (const float*)d_in[6];
  const float* bb_ = (const float*)d_in[7];
  float* out = (float*)d_out;

  unsigned short* gx4 = (unsigned short*)d_ws;                        // 100663296 B
  unsigned short* Wtb = (unsigned short*)((char*)d_ws + 100663296);   // 786432 B
  unsigned short* Upk = (unsigned short*)((char*)d_ws + 100663296 + 786432);  // 786432 B

  hipMemsetAsync(d_out, 0, (size_t)out_size * sizeof(float), stream);

  wt_prep_kernel<<<1536, 256, 0, stream>>>(Wf, Wb, Wtb);
  u_prep_kernel<<<192, 256, 0, stream>>>(Uf, Ub, Upk);
  gx_mfma_kernel<<<dim3(256, 12), 256, 0, stream>>>(x, emb, Wtb, bf_, bb_, gx4);
  gru_kernel<<<32, 512, 0, stream>>>(Upk, gx4, x, bf_, bb_, out);
}